// Round 2
// baseline (361.908 us; speedup 1.0000x reference)
//
#include <hip/hip_runtime.h>

#define DIM 64
#define NB 4096
#define NTOK 32
#define NL 2

typedef __attribute__((ext_vector_type(8))) __bf16 bf16x8;
typedef __attribute__((ext_vector_type(4))) float f32x4;

__device__ __forceinline__ f32x4 mfma16(bf16x8 a, bf16x8 b, f32x4 c) {
  return __builtin_amdgcn_mfma_f32_16x16x32_bf16(a, b, c, 0, 0, 0);
}

// ws layout (bf16 elems): [0,24576) weights-T, [24576, 24576+6.4M) ent bf16,
// then 2048 rel bf16.
#define WT_OFF   0
#define ENTB_OFF 24576
#define RELB_OFF (24576 + 100000 * 64)
#define WS_NEED_BYTES ((size_t)(RELB_OFF + 2048) * 2)

// Transpose weights to bf16 [col][k] + convert rel table.
__global__ void prep_w(const float* __restrict__ W1, const float* __restrict__ G1,
                       const float* __restrict__ W2, const float* __restrict__ G2,
                       const float* __restrict__ rel, __bf16* __restrict__ ws,
                       int do_rel) {
  int i = blockIdx.x * 256 + threadIdx.x;
  if (i < 8192) {
    int c = i >> 7, k = i & 127;
    ws[i]        = (__bf16)W1[k * 64 + c];
    ws[8192 + i] = (__bf16)G1[k * 64 + c];
  } else if (i < 12288) {
    int j = i - 8192;
    int c = j >> 6, k = j & 63;
    ws[16384 + j] = (__bf16)W2[k * 64 + c];
    ws[20480 + j] = (__bf16)G2[k * 64 + c];
  } else if (do_rel && i < 14336) {
    int j = i - 12288;
    ws[RELB_OFF + j] = (__bf16)rel[j];
  }
}

// Convert ent table f32 -> bf16 (row-major copy). 8 elems/thread.
__global__ void prep_ent(const float* __restrict__ ent, __bf16* __restrict__ entb) {
  int t = blockIdx.x * 256 + threadIdx.x;           // 800000 threads
  const float* src = ent + t * 8;
  f32x4 lo = *(const f32x4*)src;
  f32x4 hi = *(const f32x4*)(src + 4);
  bf16x8 v;
  v[0] = (__bf16)lo[0]; v[1] = (__bf16)lo[1]; v[2] = (__bf16)lo[2]; v[3] = (__bf16)lo[3];
  v[4] = (__bf16)hi[0]; v[5] = (__bf16)hi[1]; v[6] = (__bf16)hi[2]; v[7] = (__bf16)hi[3];
  *(bf16x8*)(entb + t * 8) = v;
}

// One wave = one batch element. LDS only for the GEMM1->GEMM2 transpose
// (wave-private rows) -> no __syncthreads anywhere.
template <bool BT>
__global__ __launch_bounds__(256, 3) void ckan_main(
    const int* __restrict__ items,
    const int* __restrict__ user_h, const int* __restrict__ user_r, const int* __restrict__ user_t,
    const int* __restrict__ item_h, const int* __restrict__ item_r, const int* __restrict__ item_t,
    const float* __restrict__ ent, const float* __restrict__ rel,
    const __bf16* __restrict__ wsb, const float* __restrict__ w3,
    float* __restrict__ out)
{
  __shared__ __align__(16) __bf16 s1buf[128][72];   // stride 144B: 16B-aligned rows
  __shared__ __align__(16) __bf16 g1buf[128][72];

  const int tid  = threadIdx.x;
  const int w    = tid >> 6;
  const int lane = tid & 63;
  const int b    = blockIdx.x * 4 + w;
  const int r16  = lane & 15;
  const int g4   = lane >> 4;
  const int rb   = w * 32;

  const __bf16* __restrict__ W1t = wsb;
  const __bf16* __restrict__ G1t = wsb + 8192;
  const __bf16* __restrict__ W2t = wsb + 16384;
  const __bf16* __restrict__ G2t = wsb + 20480;
  const __bf16* __restrict__ entb = wsb + ENTB_OFF;
  const __bf16* __restrict__ relb = wsb + RELB_OFF;

  // per-lane w3 columns (constant across all combos)
  float w3c[4];
#pragma unroll
  for (int n = 0; n < 4; ++n) w3c[n] = w3[n * 16 + r16];

  const f32x4 zero4 = {0.f, 0.f, 0.f, 0.f};
  float layer_dot = 0.f;

  for (int l = 0; l < NL; ++l) {
    float uvec[4];
#pragma unroll
    for (int tower = 0; tower < 2; ++tower) {
      const int* __restrict__ Hp = tower ? item_h : user_h;
      const int* __restrict__ Rp = tower ? item_r : user_r;
      const int* __restrict__ Tp = tower ? item_t : user_t;
      const int ibase = (l * NB + b) * NTOK;

      // indices loaded directly (broadcast cache lines; no LDS round-trip)
      const int h0  = Hp[ibase + r16] * DIM;
      const int h1  = Hp[ibase + 16 + r16] * DIM;
      const int rr0 = Rp[ibase + r16] * DIM;
      const int rr1 = Rp[ibase + 16 + r16] * DIM;
      int tof[2][4];                       // this lane's epilogue t-rows
#pragma unroll
      for (int m = 0; m < 2; ++m)
#pragma unroll
        for (int i = 0; i < 4; ++i)
          tof[m][i] = Tp[ibase + m * 16 + g4 * 4 + i] * DIM;

      // ---- GEMM1: x[32,128] @ {W1,G1}[128,64] ----
      f32x4 accS[2][4], accG[2][4];
#pragma unroll
      for (int m = 0; m < 2; ++m)
#pragma unroll
        for (int n = 0; n < 4; ++n) { accS[m][n] = zero4; accG[m][n] = zero4; }

#pragma unroll
      for (int kk = 0; kk < 4; ++kk) {
        bf16x8 afr[2];
#pragma unroll
        for (int m = 0; m < 2; ++m) {
          if (BT) {
            const __bf16* src = (kk < 2)
                ? entb + (m ? h1 : h0) + kk * 32 + g4 * 8
                : relb + (m ? rr1 : rr0) + (kk - 2) * 32 + g4 * 8;
            afr[m] = *(const bf16x8*)src;
          } else {
            const float* src = (kk < 2)
                ? ent + (m ? h1 : h0) + kk * 32 + g4 * 8
                : rel + (m ? rr1 : rr0) + (kk - 2) * 32 + g4 * 8;
            f32x4 lo = *(const f32x4*)(src);
            f32x4 hi = *(const f32x4*)(src + 4);
            bf16x8 a;
            a[0] = (__bf16)lo[0]; a[1] = (__bf16)lo[1]; a[2] = (__bf16)lo[2]; a[3] = (__bf16)lo[3];
            a[4] = (__bf16)hi[0]; a[5] = (__bf16)hi[1]; a[6] = (__bf16)hi[2]; a[7] = (__bf16)hi[3];
            afr[m] = a;
          }
        }
#pragma unroll
        for (int n = 0; n < 4; ++n) {
          bf16x8 bS = *(const bf16x8*)(W1t + (n * 16 + r16) * 128 + kk * 32 + g4 * 8);
          bf16x8 bG = *(const bf16x8*)(G1t + (n * 16 + r16) * 128 + kk * 32 + g4 * 8);
#pragma unroll
          for (int m = 0; m < 2; ++m) {
            accS[m][n] = mfma16(afr[m], bS, accS[m][n]);
            accG[m][n] = mfma16(afr[m], bG, accG[m][n]);
          }
        }
      }

      // ReLU + bf16 -> LDS (wave-private rows) for the GEMM2 transpose
#pragma unroll
      for (int m = 0; m < 2; ++m)
#pragma unroll
        for (int n = 0; n < 4; ++n)
#pragma unroll
          for (int i = 0; i < 4; ++i) {
            const int row = rb + m * 16 + g4 * 4 + i;
            const int col = n * 16 + r16;
            s1buf[row][col] = (__bf16)fmaxf(accS[m][n][i], 0.f);
            g1buf[row][col] = (__bf16)fmaxf(accG[m][n][i], 0.f);
          }

      // ---- GEMM2: s1@W2, g1@G2 (K=64) ----
      f32x4 acc2S[2][4], acc2G[2][4];
#pragma unroll
      for (int m = 0; m < 2; ++m)
#pragma unroll
        for (int n = 0; n < 4; ++n) { acc2S[m][n] = zero4; acc2G[m][n] = zero4; }
#pragma unroll
      for (int kk = 0; kk < 2; ++kk) {
        bf16x8 aS[2], aG[2];
#pragma unroll
        for (int m = 0; m < 2; ++m) {
          const int tok = rb + m * 16 + r16;
          aS[m] = *(const bf16x8*)&s1buf[tok][kk * 32 + g4 * 8];
          aG[m] = *(const bf16x8*)&g1buf[tok][kk * 32 + g4 * 8];
        }
#pragma unroll
        for (int n = 0; n < 4; ++n) {
          bf16x8 bS = *(const bf16x8*)(W2t + (n * 16 + r16) * 64 + kk * 32 + g4 * 8);
          bf16x8 bG = *(const bf16x8*)(G2t + (n * 16 + r16) * 64 + kk * 32 + g4 * 8);
#pragma unroll
          for (int m = 0; m < 2; ++m) {
            acc2S[m][n] = mfma16(aS[m], bS, acc2S[m][n]);
            acc2G[m][n] = mfma16(aG[m], bG, acc2G[m][n]);
          }
        }
      }

      // ---- s3/softmax entirely in registers ----
      // lane owns rows m*16+g4*4+i, cols n*16+r16 of s2.
      float att[2][4];
      {
        float dotp[2][4];
#pragma unroll
        for (int m = 0; m < 2; ++m)
#pragma unroll
          for (int i = 0; i < 4; ++i) {
            float d = 0.f;
#pragma unroll
            for (int n = 0; n < 4; ++n)
              d += fmaxf(acc2S[m][n][i], 0.f) * w3c[n];
            dotp[m][i] = d;
          }
        // sum over the 16 lanes of the r16 group -> full row dot
#pragma unroll
        for (int off = 1; off <= 8; off <<= 1)
#pragma unroll
          for (int m = 0; m < 2; ++m)
#pragma unroll
            for (int i = 0; i < 4; ++i)
              dotp[m][i] += __shfl_xor(dotp[m][i], off);
        float mx = -1.f;
#pragma unroll
        for (int m = 0; m < 2; ++m)
#pragma unroll
          for (int i = 0; i < 4; ++i) {
            dotp[m][i] = 1.f / (1.f + __expf(-dotp[m][i]));  // sc
            mx = fmaxf(mx, dotp[m][i]);
          }
        mx = fmaxf(mx, __shfl_xor(mx, 16));
        mx = fmaxf(mx, __shfl_xor(mx, 32));
        float sm = 0.f;
#pragma unroll
        for (int m = 0; m < 2; ++m)
#pragma unroll
          for (int i = 0; i < 4; ++i) {
            att[m][i] = __expf(dotp[m][i] - mx);
            sm += att[m][i];
          }
        sm += __shfl_xor(sm, 16);
        sm += __shfl_xor(sm, 32);
        const float inv = 1.f / sm;
#pragma unroll
        for (int m = 0; m < 2; ++m)
#pragma unroll
          for (int i = 0; i < 4; ++i) att[m][i] *= inv;
      }

      // ---- epilogue: out[d] = sum_t att[t] * 2*sigmoid(g2[t,d]) * t_e[t,d] ----
      float outn[4] = {0.f, 0.f, 0.f, 0.f};
#pragma unroll
      for (int m = 0; m < 2; ++m)
#pragma unroll
        for (int i = 0; i < 4; ++i) {
          const float at = att[m][i];
          const int to = tof[m][i];
#pragma unroll
          for (int n = 0; n < 4; ++n) {
            const float g2 = 2.f / (1.f + __expf(-acc2G[m][n][i]));
            const float te = BT ? (float)entb[to + n * 16 + r16]
                                : ent[to + n * 16 + r16];
            outn[n] += at * g2 * te;
          }
        }
#pragma unroll
      for (int n = 0; n < 4; ++n) {
        outn[n] += __shfl_xor(outn[n], 16);
        outn[n] += __shfl_xor(outn[n], 32);
      }
      if (tower == 0) {
#pragma unroll
        for (int n = 0; n < 4; ++n) uvec[n] = outn[n];
      } else {
#pragma unroll
        for (int n = 0; n < 4; ++n) layer_dot += uvec[n] * outn[n];
      }
    } // tower
  } // l

  // ---- origins + final score ----
  float uo = 0.f;
  const int ib0 = b * NTOK;
#pragma unroll 8
  for (int t = 0; t < NTOK; ++t) uo += ent[user_h[ib0 + t] * DIM + lane];
  uo *= (1.f / 32.f);
  const float io = ent[items[b] * DIM + lane];
  float part = uo * io + 0.25f * layer_dot;   // layer cols 4x-replicated
#pragma unroll
  for (int off = 32; off >= 1; off >>= 1) part += __shfl_xor(part, off);
  if (lane == 0) out[b] = 1.f / (1.f + __expf(-part));
}

extern "C" void kernel_launch(void* const* d_in, const int* in_sizes, int n_in,
                              void* d_out, int out_size, void* d_ws, size_t ws_size,
                              hipStream_t stream) {
  const int*   items  = (const int*)d_in[1];
  const int*   user_h = (const int*)d_in[2];
  const int*   user_r = (const int*)d_in[3];
  const int*   user_t = (const int*)d_in[4];
  const int*   item_h = (const int*)d_in[5];
  const int*   item_r = (const int*)d_in[6];
  const int*   item_t = (const int*)d_in[7];
  const float* ent    = (const float*)d_in[8];
  const float* rel    = (const float*)d_in[9];
  const float* W1     = (const float*)d_in[10];
  const float* W2     = (const float*)d_in[11];
  const float* w3     = (const float*)d_in[12];
  const float* G1     = (const float*)d_in[13];
  const float* G2     = (const float*)d_in[14];
  __bf16* wsb = (__bf16*)d_ws;
  float* out = (float*)d_out;

  const bool bt = ws_size >= WS_NEED_BYTES;
  prep_w<<<dim3(56), dim3(256), 0, stream>>>(W1, G1, W2, G2, rel, wsb, bt ? 1 : 0);
  if (bt) {
    prep_ent<<<dim3(3125), dim3(256), 0, stream>>>(ent, wsb + ENTB_OFF);
    ckan_main<true><<<dim3(NB / 4), dim3(256), 0, stream>>>(
        items, user_h, user_r, user_t, item_h, item_r, item_t,
        ent, rel, wsb, w3, out);
  } else {
    ckan_main<false><<<dim3(NB / 4), dim3(256), 0, stream>>>(
        items, user_h, user_r, user_t, item_h, item_r, item_t,
        ent, rel, wsb, w3, out);
  }
}

// Round 3
// 171.411 us; speedup vs baseline: 2.1113x; 2.1113x over previous
//
#include <hip/hip_runtime.h>

#define DIM 64
#define NB 4096
#define NTOK 32
#define NL 2

typedef __attribute__((ext_vector_type(8))) __bf16 bf16x8;
typedef __attribute__((ext_vector_type(4))) float f32x4;

__device__ __forceinline__ f32x4 mfma16(bf16x8 a, bf16x8 b, f32x4 c) {
  return __builtin_amdgcn_mfma_f32_16x16x32_bf16(a, b, c, 0, 0, 0);
}

// ws layout (bf16 elems): [0,24576) weights-T, [24576, 24576+6.4M) ent bf16,
// then 2048 rel bf16.
#define WT_OFF   0
#define ENTB_OFF 24576
#define RELB_OFF (24576 + 100000 * 64)
#define WS_NEED_BYTES ((size_t)(RELB_OFF + 2048) * 2)

// Transpose weights to bf16 [col][k] + convert rel table.
__global__ void prep_w(const float* __restrict__ W1, const float* __restrict__ G1,
                       const float* __restrict__ W2, const float* __restrict__ G2,
                       const float* __restrict__ rel, __bf16* __restrict__ ws,
                       int do_rel) {
  int i = blockIdx.x * 256 + threadIdx.x;
  if (i < 8192) {
    int c = i >> 7, k = i & 127;
    ws[i]        = (__bf16)W1[k * 64 + c];
    ws[8192 + i] = (__bf16)G1[k * 64 + c];
  } else if (i < 12288) {
    int j = i - 8192;
    int c = j >> 6, k = j & 63;
    ws[16384 + j] = (__bf16)W2[k * 64 + c];
    ws[20480 + j] = (__bf16)G2[k * 64 + c];
  } else if (do_rel && i < 14336) {
    int j = i - 12288;
    ws[RELB_OFF + j] = (__bf16)rel[j];
  }
}

// Convert ent table f32 -> bf16 (row-major copy). 8 elems/thread.
__global__ void prep_ent(const float* __restrict__ ent, __bf16* __restrict__ entb) {
  int t = blockIdx.x * 256 + threadIdx.x;           // 800000 threads
  const float* src = ent + t * 8;
  f32x4 lo = *(const f32x4*)src;
  f32x4 hi = *(const f32x4*)(src + 4);
  bf16x8 v;
  v[0] = (__bf16)lo[0]; v[1] = (__bf16)lo[1]; v[2] = (__bf16)lo[2]; v[3] = (__bf16)lo[3];
  v[4] = (__bf16)hi[0]; v[5] = (__bf16)hi[1]; v[6] = (__bf16)hi[2]; v[7] = (__bf16)hi[3];
  *(bf16x8*)(entb + t * 8) = v;
}

// One wave = one batch element. LDS only for the GEMM1->GEMM2 transpose
// (wave-private rows) -> no __syncthreads anywhere.
// launch_bounds(256,2): VGPR cap 256. (256,3) forced spills: 547 MB scratch
// writes, 2.7x slower (round-2 post-mortem).
template <bool BT>
__global__ __launch_bounds__(256, 2) void ckan_main(
    const int* __restrict__ items,
    const int* __restrict__ user_h, const int* __restrict__ user_r, const int* __restrict__ user_t,
    const int* __restrict__ item_h, const int* __restrict__ item_r, const int* __restrict__ item_t,
    const float* __restrict__ ent, const float* __restrict__ rel,
    const __bf16* __restrict__ wsb, const float* __restrict__ w3,
    float* __restrict__ out)
{
  __shared__ __align__(16) __bf16 s1buf[128][72];   // stride 144B: 16B-aligned rows
  __shared__ __align__(16) __bf16 g1buf[128][72];

  const int tid  = threadIdx.x;
  const int w    = tid >> 6;
  const int lane = tid & 63;
  const int b    = blockIdx.x * 4 + w;
  const int r16  = lane & 15;
  const int g4   = lane >> 4;
  const int rb   = w * 32;

  const __bf16* __restrict__ W1t = wsb;
  const __bf16* __restrict__ G1t = wsb + 8192;
  const __bf16* __restrict__ W2t = wsb + 16384;
  const __bf16* __restrict__ G2t = wsb + 20480;
  const __bf16* __restrict__ entb = wsb + ENTB_OFF;
  const __bf16* __restrict__ relb = wsb + RELB_OFF;

  // per-lane w3 columns (constant across all combos)
  float w3c[4];
#pragma unroll
  for (int n = 0; n < 4; ++n) w3c[n] = w3[n * 16 + r16];

  const f32x4 zero4 = {0.f, 0.f, 0.f, 0.f};
  float layer_dot = 0.f;

  for (int l = 0; l < NL; ++l) {
    float uvec[4];
#pragma unroll
    for (int tower = 0; tower < 2; ++tower) {
      const int* __restrict__ Hp = tower ? item_h : user_h;
      const int* __restrict__ Rp = tower ? item_r : user_r;
      const int* __restrict__ Tp = tower ? item_t : user_t;
      const int ibase = (l * NB + b) * NTOK;

      // indices loaded directly (broadcast cache lines; no LDS round-trip)
      const int h0  = Hp[ibase + r16] * DIM;
      const int h1  = Hp[ibase + 16 + r16] * DIM;
      const int rr0 = Rp[ibase + r16] * DIM;
      const int rr1 = Rp[ibase + 16 + r16] * DIM;

      // ---- GEMM1: x[32,128] @ {W1,G1}[128,64] ----
      f32x4 accS[2][4], accG[2][4];
#pragma unroll
      for (int m = 0; m < 2; ++m)
#pragma unroll
        for (int n = 0; n < 4; ++n) { accS[m][n] = zero4; accG[m][n] = zero4; }

#pragma unroll
      for (int kk = 0; kk < 4; ++kk) {
        bf16x8 afr[2];
#pragma unroll
        for (int m = 0; m < 2; ++m) {
          if (BT) {
            const __bf16* src = (kk < 2)
                ? entb + (m ? h1 : h0) + kk * 32 + g4 * 8
                : relb + (m ? rr1 : rr0) + (kk - 2) * 32 + g4 * 8;
            afr[m] = *(const bf16x8*)src;
          } else {
            const float* src = (kk < 2)
                ? ent + (m ? h1 : h0) + kk * 32 + g4 * 8
                : rel + (m ? rr1 : rr0) + (kk - 2) * 32 + g4 * 8;
            f32x4 lo = *(const f32x4*)(src);
            f32x4 hi = *(const f32x4*)(src + 4);
            bf16x8 a;
            a[0] = (__bf16)lo[0]; a[1] = (__bf16)lo[1]; a[2] = (__bf16)lo[2]; a[3] = (__bf16)lo[3];
            a[4] = (__bf16)hi[0]; a[5] = (__bf16)hi[1]; a[6] = (__bf16)hi[2]; a[7] = (__bf16)hi[3];
            afr[m] = a;
          }
        }
#pragma unroll
        for (int n = 0; n < 4; ++n) {
          bf16x8 bS = *(const bf16x8*)(W1t + (n * 16 + r16) * 128 + kk * 32 + g4 * 8);
          bf16x8 bG = *(const bf16x8*)(G1t + (n * 16 + r16) * 128 + kk * 32 + g4 * 8);
#pragma unroll
          for (int m = 0; m < 2; ++m) {
            accS[m][n] = mfma16(afr[m], bS, accS[m][n]);
            accG[m][n] = mfma16(afr[m], bG, accG[m][n]);
          }
        }
      }

      // ReLU + bf16 -> LDS (wave-private rows) for the GEMM2 transpose
#pragma unroll
      for (int m = 0; m < 2; ++m)
#pragma unroll
        for (int n = 0; n < 4; ++n)
#pragma unroll
          for (int i = 0; i < 4; ++i) {
            const int row = rb + m * 16 + g4 * 4 + i;
            const int col = n * 16 + r16;
            s1buf[row][col] = (__bf16)fmaxf(accS[m][n][i], 0.f);
            g1buf[row][col] = (__bf16)fmaxf(accG[m][n][i], 0.f);
          }

      // ---- GEMM2: s1@W2, g1@G2 (K=64) ----
      f32x4 acc2S[2][4], acc2G[2][4];
#pragma unroll
      for (int m = 0; m < 2; ++m)
#pragma unroll
        for (int n = 0; n < 4; ++n) { acc2S[m][n] = zero4; acc2G[m][n] = zero4; }
#pragma unroll
      for (int kk = 0; kk < 2; ++kk) {
        bf16x8 aS[2], aG[2];
#pragma unroll
        for (int m = 0; m < 2; ++m) {
          const int tok = rb + m * 16 + r16;
          aS[m] = *(const bf16x8*)&s1buf[tok][kk * 32 + g4 * 8];
          aG[m] = *(const bf16x8*)&g1buf[tok][kk * 32 + g4 * 8];
        }
#pragma unroll
        for (int n = 0; n < 4; ++n) {
          bf16x8 bS = *(const bf16x8*)(W2t + (n * 16 + r16) * 64 + kk * 32 + g4 * 8);
          bf16x8 bG = *(const bf16x8*)(G2t + (n * 16 + r16) * 64 + kk * 32 + g4 * 8);
#pragma unroll
          for (int m = 0; m < 2; ++m) {
            acc2S[m][n] = mfma16(aS[m], bS, acc2S[m][n]);
            acc2G[m][n] = mfma16(aG[m], bG, acc2G[m][n]);
          }
        }
      }

      // ---- s3/softmax entirely in registers ----
      // lane owns rows m*16+g4*4+i, cols n*16+r16 of s2.
      float att[2][4];
      {
        float dotp[2][4];
#pragma unroll
        for (int m = 0; m < 2; ++m)
#pragma unroll
          for (int i = 0; i < 4; ++i) {
            float d = 0.f;
#pragma unroll
            for (int n = 0; n < 4; ++n)
              d += fmaxf(acc2S[m][n][i], 0.f) * w3c[n];
            dotp[m][i] = d;
          }
        // sum over the 16 lanes of the r16 group -> full row dot
#pragma unroll
        for (int off = 1; off <= 8; off <<= 1)
#pragma unroll
          for (int m = 0; m < 2; ++m)
#pragma unroll
            for (int i = 0; i < 4; ++i)
              dotp[m][i] += __shfl_xor(dotp[m][i], off);
        float mx = -1.f;
#pragma unroll
        for (int m = 0; m < 2; ++m)
#pragma unroll
          for (int i = 0; i < 4; ++i) {
            dotp[m][i] = 1.f / (1.f + __expf(-dotp[m][i]));  // sc
            mx = fmaxf(mx, dotp[m][i]);
          }
        mx = fmaxf(mx, __shfl_xor(mx, 16));
        mx = fmaxf(mx, __shfl_xor(mx, 32));
        float sm = 0.f;
#pragma unroll
        for (int m = 0; m < 2; ++m)
#pragma unroll
          for (int i = 0; i < 4; ++i) {
            att[m][i] = __expf(dotp[m][i] - mx);
            sm += att[m][i];
          }
        sm += __shfl_xor(sm, 16);
        sm += __shfl_xor(sm, 32);
        const float inv = 1.f / sm;
#pragma unroll
        for (int m = 0; m < 2; ++m)
#pragma unroll
          for (int i = 0; i < 4; ++i) att[m][i] *= inv;
      }

      // ---- epilogue: out[d] = sum_t att[t] * 2*sigmoid(g2[t,d]) * t_e[t,d] ----
      float outn[4] = {0.f, 0.f, 0.f, 0.f};
#pragma unroll
      for (int m = 0; m < 2; ++m)
#pragma unroll
        for (int i = 0; i < 4; ++i) {
          const float at = att[m][i];
          const int to = Tp[ibase + m * 16 + g4 * 4 + i] * DIM;
#pragma unroll
          for (int n = 0; n < 4; ++n) {
            const float g2 = 2.f / (1.f + __expf(-acc2G[m][n][i]));
            const float te = BT ? (float)entb[to + n * 16 + r16]
                                : ent[to + n * 16 + r16];
            outn[n] += at * g2 * te;
          }
        }
#pragma unroll
      for (int n = 0; n < 4; ++n) {
        outn[n] += __shfl_xor(outn[n], 16);
        outn[n] += __shfl_xor(outn[n], 32);
      }
      if (tower == 0) {
#pragma unroll
        for (int n = 0; n < 4; ++n) uvec[n] = outn[n];
      } else {
#pragma unroll
        for (int n = 0; n < 4; ++n) layer_dot += uvec[n] * outn[n];
      }
    } // tower
  } // l

  // ---- origins + final score ----
  float uo = 0.f;
  const int ib0 = b * NTOK;
#pragma unroll 8
  for (int t = 0; t < NTOK; ++t) uo += ent[user_h[ib0 + t] * DIM + lane];
  uo *= (1.f / 32.f);
  const float io = ent[items[b] * DIM + lane];
  float part = uo * io + 0.25f * layer_dot;   // layer cols 4x-replicated
#pragma unroll
  for (int off = 32; off >= 1; off >>= 1) part += __shfl_xor(part, off);
  if (lane == 0) out[b] = 1.f / (1.f + __expf(-part));
}

extern "C" void kernel_launch(void* const* d_in, const int* in_sizes, int n_in,
                              void* d_out, int out_size, void* d_ws, size_t ws_size,
                              hipStream_t stream) {
  const int*   items  = (const int*)d_in[1];
  const int*   user_h = (const int*)d_in[2];
  const int*   user_r = (const int*)d_in[3];
  const int*   user_t = (const int*)d_in[4];
  const int*   item_h = (const int*)d_in[5];
  const int*   item_r = (const int*)d_in[6];
  const int*   item_t = (const int*)d_in[7];
  const float* ent    = (const float*)d_in[8];
  const float* rel    = (const float*)d_in[9];
  const float* W1     = (const float*)d_in[10];
  const float* W2     = (const float*)d_in[11];
  const float* w3     = (const float*)d_in[12];
  const float* G1     = (const float*)d_in[13];
  const float* G2     = (const float*)d_in[14];
  __bf16* wsb = (__bf16*)d_ws;
  float* out = (float*)d_out;

  const bool bt = ws_size >= WS_NEED_BYTES;
  prep_w<<<dim3(56), dim3(256), 0, stream>>>(W1, G1, W2, G2, rel, wsb, bt ? 1 : 0);
  if (bt) {
    prep_ent<<<dim3(3125), dim3(256), 0, stream>>>(ent, wsb + ENTB_OFF);
    ckan_main<true><<<dim3(NB / 4), dim3(256), 0, stream>>>(
        items, user_h, user_r, user_t, item_h, item_r, item_t,
        ent, rel, wsb, w3, out);
  } else {
    ckan_main<false><<<dim3(NB / 4), dim3(256), 0, stream>>>(
        items, user_h, user_r, user_t, item_h, item_r, item_t,
        ent, rel, wsb, w3, out);
  }
}